// Round 12
// baseline (311.161 us; speedup 1.0000x reference)
//
#include <hip/hip_runtime.h>
#include <math.h>

#define N_NODES 50000
#define N_EDGES 800000
#define SCAN_NB ((N_NODES + 255) / 256)   // 196
#define VOCAB   30000
#define NT32    ((N_NODES + 31) / 32)     // 1563
#define NTT     ((VOCAB + 31) / 32)       // 938

typedef __attribute__((ext_vector_type(8)))  short bf16x8;
typedef __attribute__((ext_vector_type(4)))  float f32x4;
typedef __attribute__((ext_vector_type(16))) float f32x16;
typedef __attribute__((ext_vector_type(4)))  int   i32x4;

__device__ inline short f2bf(float f) {
    union { float f; unsigned u; } v; v.f = f;
    unsigned r = v.u + 0x7FFFu + ((v.u >> 16) & 1u);   // RNE
    return (short)(r >> 16);
}
__device__ inline float bflo(unsigned u) { union { unsigned u; float f; } v; v.u = u << 16; return v.f; }
__device__ inline float bfhi(unsigned u) { union { unsigned u; float f; } v; v.u = u & 0xffff0000u; return v.f; }
__device__ inline unsigned cvtpk(float a, float b) {   // lo=bf16(a), hi=bf16(b), RNE
    unsigned r; asm("v_cvt_pk_bf16_f32 %0, %1, %2" : "=v"(r) : "v"(a), "v"(b)); return r;
}
__device__ inline float exp2neg(float x) { float r; asm("v_exp_f32 %0, -%1" : "=v"(r) : "v"(x)); return r; }
__device__ inline float exp2p(float x)   { float r; asm("v_exp_f32 %0, %1"  : "=v"(r) : "v"(x)); return r; }

__device__ inline f32x4 mfma16(bf16x8 a, bf16x8 b, f32x4 c) {
    return __builtin_amdgcn_mfma_f32_16x16x32_bf16(a, b, c, 0, 0, 0);
}
__device__ inline f32x16 mfma32(bf16x8 a, bf16x8 b, f32x16 c) {
    return __builtin_amdgcn_mfma_f32_32x32x16_bf16(a, b, c, 0, 0, 0);
}
__device__ inline bf16x8 asbf(i32x4 v) { union { i32x4 i; bf16x8 b; } u; u.i = v; return u.b; }

// ================================================================ CSR build
__global__ void k_count(const int* __restrict__ ei, int* __restrict__ cnt) {
    int e = blockIdx.x * 256 + threadIdx.x;
    if (e < N_EDGES) atomicAdd(&cnt[ei[N_EDGES + e]], 1);
}
__global__ void k_scan_local(const int* __restrict__ cnt, int* __restrict__ excl,
                             int* __restrict__ bsum) {
    __shared__ int s[256];
    int tid = threadIdx.x;
    int i = blockIdx.x * 256 + tid;
    int v = (i < N_NODES) ? cnt[i] : 0;
    s[tid] = v;
    __syncthreads();
    #pragma unroll
    for (int off = 1; off < 256; off <<= 1) {
        int t = (tid >= off) ? s[tid - off] : 0;
        __syncthreads();
        s[tid] += t;
        __syncthreads();
    }
    if (i < N_NODES) excl[i] = s[tid] - v;
    if (tid == 255) bsum[blockIdx.x] = s[255];
}
__global__ void k_scan_bsum(int* __restrict__ bsum) {
    __shared__ int s[256];
    int tid = threadIdx.x;
    int v = (tid < SCAN_NB) ? bsum[tid] : 0;
    s[tid] = v;
    __syncthreads();
    #pragma unroll
    for (int off = 1; off < 256; off <<= 1) {
        int t = (tid >= off) ? s[tid - off] : 0;
        __syncthreads();
        s[tid] += t;
        __syncthreads();
    }
    if (tid < SCAN_NB) bsum[tid] = s[tid] - v;
}
__global__ void k_make_starts(const int* __restrict__ excl, const int* __restrict__ bsum,
                              const int* __restrict__ cnt,
                              int* __restrict__ starts, int* __restrict__ cursor,
                              float* __restrict__ dinv) {
    int i = blockIdx.x * 256 + threadIdx.x;
    if (i >= N_NODES) return;
    int st = excl[i] + bsum[blockIdx.x];
    starts[i] = st;
    cursor[i] = st;
    dinv[i] = rsqrtf((float)cnt[i] + 1.0f);
}
__global__ void k_fill(const int* __restrict__ ei, int* __restrict__ cursor,
                       int* __restrict__ csr_src) {
    int e = blockIdx.x * 256 + threadIdx.x;
    if (e >= N_EDGES) return;
    int c = ei[N_EDGES + e];
    int p = atomicAdd(&cursor[c], 1);
    csr_src[p] = ei[e];
}

// ================================================================ Gi table: tab[tok][192] = (emb @ W_ih^T + bias)*scale   (f32)
// gates: [0,64)=r scaled L2E (bias=b_ih+b_hh), [64,128)=z same, [128,192)=n
// scaled 2*L2E (bias=b_ih only). Same A/B k-map and C/D layout as k_gru8.
__global__ __launch_bounds__(256) void k_gitab(
    const float* __restrict__ embed,
    const float* __restrict__ w_ih,
    const float* __restrict__ b_ih, const float* __restrict__ b_hh,
    float* __restrict__ tab)
{
    __shared__ short bfw[24 * 64 * 8];   // 24KB   frag f = (gate*2+pp)*4+ks
    const int tid = threadIdx.x;
    const float L2E = 1.4426950408889634f;
    for (int u = tid; u < 1536; u += 256) {
        int l = u & 63, f = u >> 6;
        int ks = f & 3, pp = (f >> 2) & 1, gate = f >> 3;
        float sc = (gate < 2) ? L2E : 2.0f * L2E;
        int c = gate * 64 + pp * 32 + (l & 31);
        const float* src = &w_ih[c * 64 + 16 * ks + ((l >> 5) << 3)];
        short* dst = &bfw[u * 8];
        #pragma unroll
        for (int i = 0; i < 8; ++i) dst[i] = f2bf(src[i] * sc);
    }
    __syncthreads();

    const int lane = tid & 63;
    const int wave = tid >> 6;
    const int l5 = lane >> 5;
    const int cl = lane & 31;
    const int tile = blockIdx.x * 4 + wave;
    if (tile >= NTT) return;
    const int tok = min(tile * 32 + cl, VOCAB - 1);

    // A-frags: emb row, k = 16ks + 8*l5 + i
    bf16x8 fa[4];
    #pragma unroll
    for (int ks = 0; ks < 4; ++ks) {
        const float4* p = (const float4*)&embed[tok * 64 + 16 * ks + 8 * l5];
        float4 a = p[0], b = p[1];
        i32x4 t;
        t[0] = (int)cvtpk(a.x, a.y); t[1] = (int)cvtpk(a.z, a.w);
        t[2] = (int)cvtpk(b.x, b.y); t[3] = (int)cvtpk(b.z, b.w);
        fa[ks] = asbf(t);
    }

    const bf16x8* BW = (const bf16x8*)bfw;
    f32x16 a00 = (f32x16)(0.0f), a01 = (f32x16)(0.0f);
    f32x16 a10 = (f32x16)(0.0f), a11 = (f32x16)(0.0f);
    f32x16 a20 = (f32x16)(0.0f), a21 = (f32x16)(0.0f);
    #pragma unroll
    for (int ks = 0; ks < 4; ++ks) {
        a00 = mfma32(fa[ks], BW[(0 * 4 + ks) * 64 + lane], a00);
        a01 = mfma32(fa[ks], BW[(1 * 4 + ks) * 64 + lane], a01);
        a10 = mfma32(fa[ks], BW[(2 * 4 + ks) * 64 + lane], a10);
        a11 = mfma32(fa[ks], BW[(3 * 4 + ks) * 64 + lane], a11);
        a20 = mfma32(fa[ks], BW[(4 * 4 + ks) * 64 + lane], a20);
        a21 = mfma32(fa[ks], BW[(5 * 4 + ks) * 64 + lane], a21);
    }

    float bv[6];
    #pragma unroll
    for (int gate = 0; gate < 3; ++gate)
        #pragma unroll
        for (int pp = 0; pp < 2; ++pp) {
            int d = gate * 64 + pp * 32 + cl;
            bv[gate * 2 + pp] = (gate < 2) ? (b_ih[d] + b_hh[d]) * L2E
                                           : b_ih[d] * (2.0f * L2E);
        }

    #pragma unroll
    for (int g = 0; g < 16; ++g) {
        int m = (g & 3) + 8 * (g >> 2) + 4 * l5;
        int tokr = tile * 32 + m;
        if (tokr < VOCAB) {
            float* row = tab + (unsigned)tokr * 192;
            row[cl]            = a00[g] + bv[0];
            row[32 + cl]       = a01[g] + bv[1];
            row[64 + cl]       = a10[g] + bv[2];
            row[96 + cl]       = a11[g] + bv[3];
            row[128 + cl]      = a20[g] + bv[4];
            row[160 + cl]      = a21[g] + bv[5];
        }
    }
}

// ================================================================ GRU: 2 waves per 32-node tile (wave pp owns dims 32pp..32pp+31),
// Gi from table; only hh-side MFMA in the recurrence. 2 tiles per block.
__global__ __launch_bounds__(256) void k_gru12(
    const int*   __restrict__ xtext,
    const float* __restrict__ tab,
    const float* __restrict__ w_hh, const float* __restrict__ b_hh,
    unsigned* __restrict__ ht32)    // [N][32] u32: word w = dims (w, 32+w)
{
    __shared__ short whh[24 * 64 * 8];   // 24KB   frag f = (gate*2+pp)*4+ks
    __shared__ short hbuf[2][32 * 64];   // 8KB    per-tile h (A-layout, swizzled)
    __shared__ int   tokl[2][512];       // 4KB    per-tile [m][t]

    const int tid = threadIdx.x;
    const float L2E = 1.4426950408889634f;
    for (int u = tid; u < 1536; u += 256) {
        int l = u & 63, f = u >> 6;
        int ks = f & 3, pp = (f >> 2) & 1, gate = f >> 3;
        float sc = (gate < 2) ? L2E : 2.0f * L2E;
        int c = gate * 64 + pp * 32 + (l & 31);
        const float* src = &w_hh[c * 64 + 16 * ks + ((l >> 5) << 3)];
        short* dst = &whh[u * 8];
        #pragma unroll
        for (int i = 0; i < 8; ++i) dst[i] = f2bf(src[i] * sc);
    }
    for (int u = tid; u < 1024; u += 256) {
        int tb_ = u >> 9, idx = u & 511;
        int tG_ = min(blockIdx.x * 2 + tb_, NT32 - 1);
        int node = min(tG_ * 32 + (idx >> 4), N_NODES - 1);
        tokl[tb_][idx] = xtext[node * 16 + (idx & 15)];
    }
    __syncthreads();

    const int lane = tid & 63;
    const int wave = tid >> 6;
    const int l5 = lane >> 5;
    const int cl = lane & 31;
    const int tb = wave >> 1;
    const int pp = wave & 1;
    const int tG = min(blockIdx.x * 2 + tb, NT32 - 1);
    const int nbase = tG * 32;

    const float bnh = b_hh[128 + pp * 32 + cl] * (2.0f * L2E);
    const bf16x8* WH = (const bf16x8*)whh;
    short* hl = &hbuf[tb][0];
    const int* tkp = &tokl[tb][0];
    const int dofs = pp * 32 + cl;

    float hr[16];
    #pragma unroll
    for (int g = 0; g < 16; ++g) hr[g] = 0.0f;

    #pragma unroll 1
    for (int t = 0; t < 16; ++t) {
        // Gi loads from table (independent of h; hidden under barriers/MFMA)
        float tr[16], tz[16], tn[16];
        #pragma unroll
        for (int g = 0; g < 16; ++g) {
            int m = (g & 3) + 8 * (g >> 2) + 4 * l5;
            int tk = tkp[m * 16 + t];
            const float* row = tab + (unsigned)tk * 192 + dofs;
            tr[g] = row[0];
            tz[g] = row[64];
            tn[g] = row[128];
        }
        __syncthreads();   // prev step's h writes visible
        bf16x8 hA[4];
        if (t > 0) {
            #pragma unroll
            for (int ks = 0; ks < 4; ++ks) {
                int o = (ks * 2 + l5) ^ (cl & 7);
                hA[ks] = *(const bf16x8*)&hl[cl * 64 + o * 8];
            }
        }
        __syncthreads();   // all reads done before this step's writes

        f32x16 ar, az, ah;
        #pragma unroll
        for (int g = 0; g < 16; ++g) { ar[g] = tr[g]; az[g] = tz[g]; ah[g] = bnh; }
        if (t > 0) {
            #pragma unroll
            for (int ks = 0; ks < 4; ++ks) {
                ar = mfma32(hA[ks], WH[((0 * 2 + pp) * 4 + ks) * 64 + lane], ar);
                az = mfma32(hA[ks], WH[((1 * 2 + pp) * 4 + ks) * 64 + lane], az);
                ah = mfma32(hA[ks], WH[((2 * 2 + pp) * 4 + ks) * 64 + lane], ah);
            }
        }
        #pragma unroll
        for (int g = 0; g < 16; ++g) {
            float r = __builtin_amdgcn_rcpf(1.0f + exp2neg(ar[g]));
            float z = __builtin_amdgcn_rcpf(1.0f + exp2neg(az[g]));
            float v = tn[g] + r * ah[g];
            float n = 1.0f - 2.0f * __builtin_amdgcn_rcpf(exp2p(v) + 1.0f);
            float h = n + z * (hr[g] - n);
            hr[g] = h;
            int m = (g & 3) + 8 * (g >> 2) + 4 * l5;
            int j = dofs;
            int o = (j >> 3) ^ (m & 7);
            hl[m * 64 + o * 8 + (j & 7)] = (short)cvtpk(h, h);
        }
    }
    __syncthreads();   // final h visible

    if (pp == 0 && (blockIdx.x * 2 + tb) < NT32) {
        #pragma unroll
        for (int g = 0; g < 16; ++g) {
            int m = (g & 3) + 8 * (g >> 2) + 4 * l5;
            int n_ = nbase + m;
            if (n_ < N_NODES) {
                int o1 = (4 + (cl >> 3)) ^ (m & 7);
                unsigned hi = (unsigned)(unsigned short)hl[m * 64 + o1 * 8 + (cl & 7)];
                unsigned lo = (unsigned)(unsigned short)(short)cvtpk(hr[g], hr[g]);
                ht32[(unsigned)n_ * 32 + cl] = lo | (hi << 16);
            }
        }
    }
}

// ================================================================ MFMA mm1: msb = dinv*( [x|ht] @ W1 ), K padded 72->80
__global__ __launch_bounds__(256) void k_mm1_mf(
    const float* __restrict__ x, const unsigned* __restrict__ ht32,
    const float* __restrict__ W1, const float* __restrict__ dinv,
    unsigned* __restrict__ msb)
{
    __shared__ short bfw[2 * 5 * 64 * 8];   // 10KB  frag f=p*5+ks
    const int tid = threadIdx.x;
    for (int u = tid; u < 640; u += 256) {
        int l = u & 63, f = u >> 6;
        int ks = f % 5, p = f / 5;
        int c = p * 32 + (l & 31);
        int wl5 = l >> 5;
        short* dst = &bfw[u * 8];
        if (ks < 4) {
            const float* src = &W1[(8 + ks * 16 + 8 * wl5) * 64 + c];
            #pragma unroll
            for (int i = 0; i < 8; ++i) dst[i] = f2bf(src[i * 64]);
        } else {
            #pragma unroll
            for (int i = 0; i < 8; ++i) dst[i] = (wl5 == 0) ? f2bf(W1[i * 64 + c]) : (short)0;
        }
    }
    __syncthreads();

    const int lane = tid & 63;
    const int wave = tid >> 6;
    const int l5 = lane >> 5;
    const int cl = lane & 31;
    const int tile = blockIdx.x * 4 + wave;
    if (tile >= NT32) return;
    const int nbase = tile * 32;
    const int node = min(nbase + cl, N_NODES - 1);

    const uint4* hp = (const uint4*)(ht32 + (unsigned)node * 32);
    uint4 A0 = hp[2 * l5], A1 = hp[2 * l5 + 1];
    uint4 A2 = hp[4 + 2 * l5], A3 = hp[5 + 2 * l5];
    const float4* xp = (const float4*)(x + (size_t)node * 8);
    float4 x0 = xp[0], x1 = xp[1];

    unsigned w0[8] = {A0.x, A0.y, A0.z, A0.w, A1.x, A1.y, A1.z, A1.w};
    unsigned w1[8] = {A2.x, A2.y, A2.z, A2.w, A3.x, A3.y, A3.z, A3.w};

    bf16x8 fa[5];
    {
        i32x4 t;
        #pragma unroll
        for (int i = 0; i < 4; ++i) t[i] = (int)((w0[2*i] & 0xffffu) | (w0[2*i+1] << 16));
        fa[0] = asbf(t);
        #pragma unroll
        for (int i = 0; i < 4; ++i) t[i] = (int)((w1[2*i] & 0xffffu) | (w1[2*i+1] << 16));
        fa[1] = asbf(t);
        #pragma unroll
        for (int i = 0; i < 4; ++i) t[i] = (int)((w0[2*i] >> 16) | (w0[2*i+1] & 0xffff0000u));
        fa[2] = asbf(t);
        #pragma unroll
        for (int i = 0; i < 4; ++i) t[i] = (int)((w1[2*i] >> 16) | (w1[2*i+1] & 0xffff0000u));
        fa[3] = asbf(t);
        if (l5 == 0) {
            t[0] = (int)cvtpk(x0.x, x0.y); t[1] = (int)cvtpk(x0.z, x0.w);
            t[2] = (int)cvtpk(x1.x, x1.y); t[3] = (int)cvtpk(x1.z, x1.w);
        } else {
            t[0] = t[1] = t[2] = t[3] = 0;
        }
        fa[4] = asbf(t);
    }

    const bf16x8* BW = (const bf16x8*)bfw;
    f32x16 a0 = (f32x16)(0.0f), a1 = (f32x16)(0.0f);
    #pragma unroll
    for (int ks = 0; ks < 5; ++ks) {
        a0 = mfma32(fa[ks], BW[ks * 64 + lane], a0);
        a1 = mfma32(fa[ks], BW[(5 + ks) * 64 + lane], a1);
    }

    #pragma unroll
    for (int g = 0; g < 16; ++g) {
        int m = (g & 3) + 8 * (g >> 2) + 4 * l5;
        int n = nbase + m;
        if (n < N_NODES) {
            float dv = dinv[n];
            msb[(unsigned)n * 32 + cl] = cvtpk(a0[g] * dv, a1[g] * dv);
        }
    }
}

// ================================================================ MFMA mm2: msb = dinv*(h1 @ W2), h1 packed in
__global__ __launch_bounds__(256) void k_mm2_mf(
    const unsigned* __restrict__ h1b, const float* __restrict__ W2,
    const float* __restrict__ dinv, unsigned* __restrict__ msb)
{
    __shared__ short bfw[2 * 4 * 64 * 8];   // 8KB  frag f=p*4+ks
    const int tid = threadIdx.x;
    for (int u = tid; u < 512; u += 256) {
        int l = u & 63, f = u >> 6;
        int ks = f & 3, p = f >> 2;
        int c = p * 32 + (l & 31);
        int wl5 = l >> 5;
        const float* src = &W2[(ks * 16 + 8 * wl5) * 64 + c];
        short* dst = &bfw[u * 8];
        #pragma unroll
        for (int i = 0; i < 8; ++i) dst[i] = f2bf(src[i * 64]);
    }
    __syncthreads();

    const int lane = tid & 63;
    const int wave = tid >> 6;
    const int l5 = lane >> 5;
    const int cl = lane & 31;
    const int tile = blockIdx.x * 4 + wave;
    if (tile >= NT32) return;
    const int nbase = tile * 32;
    const int node = min(nbase + cl, N_NODES - 1);

    const uint4* hp = (const uint4*)(h1b + (unsigned)node * 32);
    uint4 A0 = hp[2 * l5], A1 = hp[2 * l5 + 1];
    uint4 A2 = hp[4 + 2 * l5], A3 = hp[5 + 2 * l5];

    unsigned w0[8] = {A0.x, A0.y, A0.z, A0.w, A1.x, A1.y, A1.z, A1.w};
    unsigned w1[8] = {A2.x, A2.y, A2.z, A2.w, A3.x, A3.y, A3.z, A3.w};

    bf16x8 fa[4];
    {
        i32x4 t;
        #pragma unroll
        for (int i = 0; i < 4; ++i) t[i] = (int)((w0[2*i] & 0xffffu) | (w0[2*i+1] << 16));
        fa[0] = asbf(t);
        #pragma unroll
        for (int i = 0; i < 4; ++i) t[i] = (int)((w1[2*i] & 0xffffu) | (w1[2*i+1] << 16));
        fa[1] = asbf(t);
        #pragma unroll
        for (int i = 0; i < 4; ++i) t[i] = (int)((w0[2*i] >> 16) | (w0[2*i+1] & 0xffff0000u));
        fa[2] = asbf(t);
        #pragma unroll
        for (int i = 0; i < 4; ++i) t[i] = (int)((w1[2*i] >> 16) | (w1[2*i+1] & 0xffff0000u));
        fa[3] = asbf(t);
    }

    const bf16x8* BW = (const bf16x8*)bfw;
    f32x16 a0 = (f32x16)(0.0f), a1 = (f32x16)(0.0f);
    #pragma unroll
    for (int ks = 0; ks < 4; ++ks) {
        a0 = mfma32(fa[ks], BW[ks * 64 + lane], a0);
        a1 = mfma32(fa[ks], BW[(4 + ks) * 64 + lane], a1);
    }

    #pragma unroll
    for (int g = 0; g < 16; ++g) {
        int m = (g & 3) + 8 * (g >> 2) + 4 * l5;
        int n = nbase + m;
        if (n < N_NODES) {
            float dv = dinv[n];
            msb[(unsigned)n * 32 + cl] = cvtpk(a0[g] * dv, a1[g] * dv);
        }
    }
}

// ================================================================ gather (packed bf16 in/out): 2 nodes/wave, 32 lanes each
__global__ __launch_bounds__(256) void k_gather_p(
    const unsigned* __restrict__ msb, const int* __restrict__ csr_src,
    const int* __restrict__ starts, const int* __restrict__ cnt,
    const float* __restrict__ dinv, const float* __restrict__ b,
    unsigned* __restrict__ outp)
{
    int n = blockIdx.x * 8 + (threadIdx.x >> 5);
    if (n >= N_NODES) return;
    int w = threadIdx.x & 31;
    int c = cnt[n];
    const int* lst = csr_src + starts[n];
    unsigned us = msb[(unsigned)n * 32 + w];
    float a0 = bflo(us), a1 = bfhi(us);
    int k = 0;
    for (; k + 4 <= c; k += 4) {
        int r0 = lst[k], r1 = lst[k+1], r2 = lst[k+2], r3 = lst[k+3];
        unsigned u0 = msb[(unsigned)r0 * 32 + w];
        unsigned u1 = msb[(unsigned)r1 * 32 + w];
        unsigned u2 = msb[(unsigned)r2 * 32 + w];
        unsigned u3 = msb[(unsigned)r3 * 32 + w];
        a0 += bflo(u0) + bflo(u1) + bflo(u2) + bflo(u3);
        a1 += bfhi(u0) + bfhi(u1) + bfhi(u2) + bfhi(u3);
    }
    for (; k < c; ++k) {
        unsigned u = msb[(unsigned)lst[k] * 32 + w];
        a0 += bflo(u); a1 += bfhi(u);
    }
    float d = dinv[n];
    float v0 = fmaxf(d * a0 + b[w], 0.0f);
    float v1 = fmaxf(d * a1 + b[w + 32], 0.0f);
    outp[(unsigned)n * 32 + w] = cvtpk(v0, v1);
}

// ================================================================ gather writing true-order bf16 rows (feeds edge classifier)
__global__ __launch_bounds__(256) void k_gather_h2(
    const unsigned* __restrict__ msb, const int* __restrict__ csr_src,
    const int* __restrict__ starts, const int* __restrict__ cnt,
    const float* __restrict__ dinv, const float* __restrict__ b,
    short* __restrict__ out)
{
    int n = blockIdx.x * 8 + (threadIdx.x >> 5);
    if (n >= N_NODES) return;
    int w = threadIdx.x & 31;
    int c = cnt[n];
    const int* lst = csr_src + starts[n];
    unsigned us = msb[(unsigned)n * 32 + w];
    float a0 = bflo(us), a1 = bfhi(us);
    int k = 0;
    for (; k + 4 <= c; k += 4) {
        int r0 = lst[k], r1 = lst[k+1], r2 = lst[k+2], r3 = lst[k+3];
        unsigned u0 = msb[(unsigned)r0 * 32 + w];
        unsigned u1 = msb[(unsigned)r1 * 32 + w];
        unsigned u2 = msb[(unsigned)r2 * 32 + w];
        unsigned u3 = msb[(unsigned)r3 * 32 + w];
        a0 += bflo(u0) + bflo(u1) + bflo(u2) + bflo(u3);
        a1 += bfhi(u0) + bfhi(u1) + bfhi(u2) + bfhi(u3);
    }
    for (; k < c; ++k) {
        unsigned u = msb[(unsigned)lst[k] * 32 + w];
        a0 += bflo(u); a1 += bfhi(u);
    }
    float d = dinv[n];
    float v0 = fmaxf(d * a0 + b[w], 0.0f);
    float v1 = fmaxf(d * a1 + b[w + 32], 0.0f);
    unsigned u = cvtpk(v0, v1);
    out[(unsigned)n * 64 + w]      = (short)u;
    out[(unsigned)n * 64 + 32 + w] = (short)(u >> 16);
}

// ================================================================ edge classifier via MFMA (bf16 h2)
__global__ __launch_bounds__(256) void k_edge_mfma(
    const int* __restrict__ ei, const short* __restrict__ h2b,
    const float* __restrict__ Wl1, const float* __restrict__ bl1,
    const float* __restrict__ Wf,  const float* __restrict__ bf,
    float* __restrict__ out)
{
    __shared__ float wl_s[128 * 64];
    const int tid = threadIdx.x;
    for (int i = tid; i < 128 * 64; i += 256) wl_s[i] = Wl1[i];
    __syncthreads();

    const int lane = tid & 63;
    const int wave = tid >> 6;
    const int lg = lane >> 4;
    const int ll = lane & 15;

    bf16x8 B[16];
    #pragma unroll
    for (int ks = 0; ks < 4; ++ks) {
        #pragma unroll
        for (int ct = 0; ct < 4; ++ct) {
            int c  = ct * 16 + ll;
            int kb = ks * 32 + 8 * lg;
            bf16x8 v;
            #pragma unroll
            for (int i = 0; i < 8; ++i) v[i] = f2bf(wl_s[(kb + i) * 64 + c]);
            B[ks * 4 + ct] = v;
        }
    }
    float wf0[4], wf1[4], bl[4];
    #pragma unroll
    for (int ct = 0; ct < 4; ++ct) {
        int c = ct * 16 + ll;
        wf0[ct] = Wf[c * 2 + 0];
        wf1[ct] = Wf[c * 2 + 1];
        bl[ct]  = bl1[c];
    }
    const float bf0 = bf[0], bf1 = bf[1];

    for (int tile = blockIdx.x * 4 + wave; tile < N_EDGES / 16; tile += gridDim.x * 4) {
        const int ebase = tile * 16;
        const int erow  = ebase + ll;
        const int src = ei[erow];
        const int dst = ei[N_EDGES + erow];

        f32x4 acc[4];
        #pragma unroll
        for (int ct = 0; ct < 4; ++ct) acc[ct] = (f32x4){bl[ct], bl[ct], bl[ct], bl[ct]};

        #pragma unroll
        for (int ks = 0; ks < 4; ++ks) {
            const int nd = (ks < 2) ? src : dst;
            bf16x8 A = *(const bf16x8*)&h2b[nd * 64 + (ks & 1) * 32 + 8 * lg];
            #pragma unroll
            for (int ct = 0; ct < 4; ++ct) acc[ct] = mfma16(A, B[ks * 4 + ct], acc[ct]);
        }

        float p0[4], p1[4];
        #pragma unroll
        for (int q = 0; q < 4; ++q) { p0[q] = 0.0f; p1[q] = 0.0f; }
        #pragma unroll
        for (int ct = 0; ct < 4; ++ct) {
            #pragma unroll
            for (int q = 0; q < 4; ++q) {
                float hd = fmaxf(acc[ct][q], 0.0f);
                p0[q] += hd * wf0[ct];
                p1[q] += hd * wf1[ct];
            }
        }
        #pragma unroll
        for (int m = 1; m <= 8; m <<= 1) {
            #pragma unroll
            for (int q = 0; q < 4; ++q) {
                p0[q] += __shfl_xor(p0[q], m, 64);
                p1[q] += __shfl_xor(p1[q], m, 64);
            }
        }
        if (ll < 8) {
            int q = ll >> 1, cls = ll & 1;
            float l0 = p0[q] + bf0, l1 = p1[q] + bf1;
            float mx  = fmaxf(l0, l1);
            float lse = mx + __logf(__expf(l0 - mx) + __expf(l1 - mx));
            float val = (cls ? l1 : l0) - lse;
            out[(ebase + 4 * lg + q) * 2 + cls] = val;
        }
    }
}

// ================================================================ launch
extern "C" void kernel_launch(void* const* d_in, const int* in_sizes, int n_in,
                              void* d_out, int out_size, void* d_ws, size_t ws_size,
                              hipStream_t stream) {
    const float* x     = (const float*)d_in[0];
    const int*   ei    = (const int*)  d_in[1];
    const int*   xtext = (const int*)  d_in[2];
    const float* embed = (const float*)d_in[3];
    const float* w_ih  = (const float*)d_in[4];
    const float* w_hh  = (const float*)d_in[5];
    const float* b_ih  = (const float*)d_in[6];
    const float* b_hh  = (const float*)d_in[7];
    const float* W1    = (const float*)d_in[8];
    const float* b1    = (const float*)d_in[9];
    const float* W2    = (const float*)d_in[10];
    const float* b2    = (const float*)d_in[11];
    const float* Wl1   = (const float*)d_in[12];
    const float* bl1   = (const float*)d_in[13];
    const float* Wf    = (const float*)d_in[14];
    const float* bf    = (const float*)d_in[15];
    float* out = (float*)d_out;

    char* ws = (char*)d_ws;
    size_t off = 0;
    auto alloc = [&](size_t bytes) { char* p = ws + off; off += (bytes + 255) & ~size_t(255); return p; };
    unsigned* ht32   = (unsigned*)alloc(N_NODES * 32 * 4);
    unsigned* msb    = (unsigned*)alloc(N_NODES * 32 * 4);
    unsigned* h1b    = (unsigned*)alloc(N_NODES * 32 * 4);
    short*    h2b    = (short*)   alloc(N_NODES * 64 * 2);
    float*    dinv   = (float*)   alloc(N_NODES * 4);
    int*      cnt    = (int*)     alloc(N_NODES * 4);
    int*      excl   = (int*)     alloc(N_NODES * 4);
    int*      starts = (int*)     alloc(N_NODES * 4);
    int*      cursor = (int*)     alloc(N_NODES * 4);
    int*      bsum   = (int*)     alloc(SCAN_NB * 4);
    int*      csr_src= (int*)     alloc(N_EDGES * 4);
    float*    tab    = (float*)   alloc((size_t)VOCAB * 192 * 4);

    // ---- Gi table (input-gate GEMM hoisted out of the recurrence)
    k_gitab<<<(NTT + 3) / 4, 256, 0, stream>>>(embed, w_ih, b_ih, b_hh, tab);

    // ---- CSR build (shared by both GCN layers)
    hipMemsetAsync(cnt, 0, N_NODES * 4, stream);
    k_count<<<(N_EDGES + 255) / 256, 256, 0, stream>>>(ei, cnt);
    k_scan_local<<<SCAN_NB, 256, 0, stream>>>(cnt, excl, bsum);
    k_scan_bsum<<<1, 256, 0, stream>>>(bsum);
    k_make_starts<<<SCAN_NB, 256, 0, stream>>>(excl, bsum, cnt, starts, cursor, dinv);
    k_fill<<<(N_EDGES + 255) / 256, 256, 0, stream>>>(ei, cursor, csr_src);

    // ---- text encoder (split-wave, table-driven recurrence)
    k_gru12<<<(NT32 + 1) / 2, 256, 0, stream>>>(xtext, tab, w_hh, b_hh, ht32);

    // ---- GCN layer 1
    k_mm1_mf<<<(NT32 + 3) / 4, 256, 0, stream>>>(x, ht32, W1, dinv, msb);
    k_gather_p<<<(N_NODES + 7) / 8, 256, 0, stream>>>(msb, csr_src, starts, cnt, dinv, b1, h1b);

    // ---- GCN layer 2
    k_mm2_mf<<<(NT32 + 3) / 4, 256, 0, stream>>>(h1b, W2, dinv, msb);
    k_gather_h2<<<(N_NODES + 7) / 8, 256, 0, stream>>>(msb, csr_src, starts, cnt, dinv, b2, h2b);

    // ---- edge classifier
    k_edge_mfma<<<2048, 256, 0, stream>>>(ei, h2b, Wl1, bl1, Wf, bf, out);
}